// Round 3
// baseline (128.979 us; speedup 1.0000x reference)
//
#include <hip/hip_runtime.h>
#include <stdint.h>

// (B,C,H,W)=(8,64,128,128), OC=64, K=3, stride=1, pad=1, fill=-1.
#define HW   128
#define CIN  64
#define OCN  64
#define NB   8

typedef __attribute__((ext_vector_type(8)))  short short8;
typedef __attribute__((ext_vector_type(16))) float floatx16;

union F8 { short8 s; uint32_t d[4]; uint4 q; };

// round-to-nearest-even f32 -> bf16 (inputs finite)
static __device__ __forceinline__ ushort f2bf(float f) {
    uint32_t u = __float_as_uint(f);
    return (ushort)((u + 0x7FFFu + ((u >> 16) & 1u)) >> 16);
}

// ---------------- prep: streaming transpose/convert ----------------
// blocks 0..1023  : one (b,y) row — NCHW fp32 -> Xb NHWC bf16 (128 B/pixel)
// blocks 1024..1032: tap t=bid-1024 — conv[oc][c][3][3] fp32 -> wb[t][oc][c] bf16
#define LROW_STR 68   // shorts per pixel in LDS transpose tile

__global__ __launch_bounds__(256)
void prep_kernel(const float* __restrict__ inp, const float* __restrict__ conv,
                 ushort* __restrict__ wb, ushort* __restrict__ xb)
{
    __shared__ ushort Ls[HW * LROW_STR];   // 17408 B
    const int bid = blockIdx.x, tid = threadIdx.x;

    if (bid >= 1024) {                      // weight transpose tail blocks
        int t = bid - 1024;
        #pragma unroll
        for (int i = 0; i < 16; ++i) {
            int id = i * 256 + tid;         // 0..4095
            int oc = id >> 6, c = id & 63;
            wb[t * 4096 + id] = f2bf(conv[(oc * 64 + c) * 9 + t]);
        }
        return;
    }

    const int bb = bid >> 7, y = bid & 127;
    const int cg = tid >> 5, xg = tid & 31;           // 8 c-groups x 32 x-groups
    const float* src = inp + ((size_t)(bb * CIN + cg * 8) * HW + y) * HW + xg * 4;
    #pragma unroll
    for (int k = 0; k < 8; ++k) {                     // c = cg*8+k, 4 px per load
        float4 v = *(const float4*)(src + (size_t)k * HW * HW);
        ushort* p = Ls + (xg * 4) * LROW_STR + cg * 8 + k;
        p[0]            = f2bf(v.x);
        p[LROW_STR]     = f2bf(v.y);
        p[2 * LROW_STR] = f2bf(v.z);
        p[3 * LROW_STR] = f2bf(v.w);
    }
    __syncthreads();
    ushort* dst = xb + (size_t)(bb * HW + y) * HW * 64;
    const int g = tid & 7, p0 = tid >> 3;             // 8 ch-groups x 32 px
    #pragma unroll
    for (int pass = 0; pass < 4; ++pass) {
        int p = pass * 32 + p0;
        uint2 a = *(const uint2*)(Ls + p * LROW_STR + g * 8);
        uint2 b = *(const uint2*)(Ls + p * LROW_STR + g * 8 + 4);
        *(uint4*)(dst + p * 64 + g * 8) = make_uint4(a.x, a.y, b.x, b.y);
    }
}

// ---------------- main: LDS-free, barrier-free, 1 wave/block ----------------
// block = (b, y, xhalf): wave computes 64 oc x 64 px via 2x2 of 32x32x16 MFMA.
// A (weights) and B (NHWC bf16 pixels) register-double-buffered from global.
static __device__ __forceinline__ void load_tap(
    const ushort* __restrict__ wb, const ushort* __restrict__ xb,
    int t, int bb, int y, int x0, int x1, int l31, int lh,
    uint4* Ar, uint4* Br)
{
    const ushort* wp = wb + t * 4096 + l31 * 64 + lh * 8;
    #pragma unroll
    for (int h = 0; h < 2; ++h)
        #pragma unroll
        for (int ks = 0; ks < 4; ++ks)
            Ar[h * 4 + ks] = *(const uint4*)(wp + h * 2048 + ks * 16);

    const int dy = t / 3 - 1, dx = t % 3 - 1;
    int ny = y + dy; ny = ny < 0 ? 0 : (ny > HW - 1 ? HW - 1 : ny);
    #pragma unroll
    for (int n = 0; n < 2; ++n) {
        int nx = (n ? x1 : x0) + dx;
        nx = nx < 0 ? 0 : (nx > HW - 1 ? HW - 1 : nx);
        const ushort* bp = xb + (((size_t)bb * HW + ny) * HW + nx) * 64 + lh * 8;
        #pragma unroll
        for (int ks = 0; ks < 4; ++ks)
            Br[n * 4 + ks] = *(const uint4*)(bp + ks * 16);
    }
}

__global__ __launch_bounds__(64, 2)
void iconv_main(const ushort* __restrict__ xb, const ushort* __restrict__ wb,
                const float* __restrict__ mask, const float* __restrict__ bias,
                float* __restrict__ out)
{
    const int bid = blockIdx.x;
    const int bb = bid >> 8, y = (bid >> 1) & 127, xw = (bid & 1) * 64;
    const int lane = threadIdx.x, l31 = lane & 31, lh = lane >> 5;
    const int x0 = xw + l31, x1 = x0 + 32;

    // ---- eq masks from global mask (rows are 512 B, L1/L2-hot) ----
    const float* mrow = mask + ((size_t)bb * HW + y) * HW;
    const float m00 = mrow[x0], m01 = mrow[x1];
    uint32_t bits0 = 0, bits1 = 0;
    #pragma unroll
    for (int t = 0; t < 9; ++t) {
        int dy = t / 3 - 1, dx = t % 3 - 1;
        int ny = y + dy;
        bool vy = (ny >= 0) && (ny < HW);
        int nyc = vy ? ny : y;
        const float* r = mask + ((size_t)bb * HW + nyc) * HW;
        int nx0 = x0 + dx, nx1 = x1 + dx;
        bool ok0 = vy && (nx0 >= 0) && (nx0 < HW);
        bool ok1 = vy && (nx1 >= 0) && (nx1 < HW);
        int c0 = nx0 < 0 ? 0 : (nx0 > HW - 1 ? HW - 1 : nx0);
        int c1 = nx1 < 0 ? 0 : (nx1 > HW - 1 ? HW - 1 : nx1);
        if (ok0 && r[c0] == m00) bits0 |= 1u << t;
        if (ok1 && r[c1] == m01) bits1 |= 1u << t;
    }
    const float norm0 = 9.0f / (float)__popc(bits0);
    const float norm1 = 9.0f / (float)__popc(bits1);

    // ---- fused mask_out (== mask) ----
    float* mout = out + (size_t)NB * OCN * HW * HW + ((size_t)bb * HW + y) * HW;
    mout[x0] = m00;
    mout[x1] = m01;

    floatx16 acc00 = {0,0,0,0,0,0,0,0,0,0,0,0,0,0,0,0};
    floatx16 acc01 = {0,0,0,0,0,0,0,0,0,0,0,0,0,0,0,0};
    floatx16 acc10 = {0,0,0,0,0,0,0,0,0,0,0,0,0,0,0,0};
    floatx16 acc11 = {0,0,0,0,0,0,0,0,0,0,0,0,0,0,0,0};

    uint4 Ar[2][8], Br[2][8];
    load_tap(wb, xb, 0, bb, y, x0, x1, l31, lh, Ar[0], Br[0]);

    #pragma unroll
    for (int t = 0; t < 9; ++t) {
        const int buf = t & 1;
        if (t < 8)   // next tap's 16 loads in flight across this tap's 16 MFMAs
            load_tap(wb, xb, t + 1, bb, y, x0, x1, l31, lh, Ar[buf ^ 1], Br[buf ^ 1]);

        const uint32_t s0 = ((bits0 >> t) & 1u) ? 0xFFFFFFFFu : 0u;
        const uint32_t s1 = ((bits1 >> t) & 1u) ? 0xFFFFFFFFu : 0u;

        #pragma unroll
        for (int ks = 0; ks < 4; ++ks) {
            F8 a0, a1, b0, b1;
            a0.q = Ar[buf][ks];
            a1.q = Ar[buf][4 + ks];
            b0.q = Br[buf][ks];
            b1.q = Br[buf][4 + ks];
            b0.d[0] &= s0; b0.d[1] &= s0; b0.d[2] &= s0; b0.d[3] &= s0;
            b1.d[0] &= s1; b1.d[1] &= s1; b1.d[2] &= s1; b1.d[3] &= s1;
            acc00 = __builtin_amdgcn_mfma_f32_32x32x16_bf16(a0.s, b0.s, acc00, 0, 0, 0);
            acc01 = __builtin_amdgcn_mfma_f32_32x32x16_bf16(a0.s, b1.s, acc01, 0, 0, 0);
            acc10 = __builtin_amdgcn_mfma_f32_32x32x16_bf16(a1.s, b0.s, acc10, 0, 0, 0);
            acc11 = __builtin_amdgcn_mfma_f32_32x32x16_bf16(a1.s, b1.s, acc11, 0, 0, 0);
        }
    }

    // ---- epilogue (C/D: col=lane&31, row=(r&3)+8*(r>>2)+4*lh) ----
    float* outp = out + (size_t)bb * OCN * HW * HW + (size_t)y * HW;
    #pragma unroll
    for (int mt = 0; mt < 2; ++mt) {
        #pragma unroll
        for (int nt = 0; nt < 2; ++nt) {
            floatx16 a = (mt == 0) ? (nt == 0 ? acc00 : acc01)
                                   : (nt == 0 ? acc10 : acc11);
            float nm = (nt == 0) ? norm0 : norm1;
            int x = xw + nt * 32 + l31;
            #pragma unroll
            for (int r = 0; r < 16; ++r) {
                int oc = mt * 32 + (r & 3) + 8 * (r >> 2) + 4 * lh;
                outp[(size_t)oc * (HW * HW) + x] = a[r] * nm + bias[oc];
            }
        }
    }
}

extern "C" void kernel_launch(void* const* d_in, const int* in_sizes, int n_in,
                              void* d_out, int out_size, void* d_ws, size_t ws_size,
                              hipStream_t stream) {
    (void)in_sizes; (void)n_in; (void)out_size; (void)ws_size;
    const float* inp  = (const float*)d_in[0];
    const float* mask = (const float*)d_in[1];
    const float* conv = (const float*)d_in[2];
    const float* bias = (const float*)d_in[3];
    float* out = (float*)d_out;

    ushort* wb = (ushort*)d_ws;               // 9*64*64 bf16 = 73,728 B
    ushort* xb = (ushort*)d_ws + 65536;       // NHWC bf16, 16.8 MB (128 KiB offset)

    prep_kernel<<<1033, 256, 0, stream>>>(inp, conv, wb, xb);
    iconv_main<<<NB * HW * 2, 64, 0, stream>>>(xb, wb, mask, bias, out);
}

// Round 4
// 117.250 us; speedup vs baseline: 1.1000x; 1.1000x over previous
//
#include <hip/hip_runtime.h>
#include <stdint.h>

// (B,C,H,W)=(8,64,128,128), OC=64, K=3, stride=1, pad=1, fill=-1.
#define HW   128
#define CIN  64
#define OCN  64
#define NB   8

typedef __attribute__((ext_vector_type(8)))  short short8;
typedef __attribute__((ext_vector_type(16))) float floatx16;

union F8 { short8 s; uint32_t d[4]; uint4 q; };

// round-to-nearest-even f32 -> bf16 (inputs finite)
static __device__ __forceinline__ ushort f2bf(float f) {
    uint32_t u = __float_as_uint(f);
    return (ushort)((u + 0x7FFFu + ((u >> 16) & 1u)) >> 16);
}

// ---------------- prep: LDS-free streaming convert/transpose ----------------
// blocks 0..1023   : one (b,y) row -> xb: bf16, pixel-major, 128 B/pixel,
//                    16 B chunk c of pixel p stored at slot c^(p&7)  (bank swizzle)
// blocks 1024..1032: tap t -> wb[t][oc][c] bf16
__global__ __launch_bounds__(256)
void prep_kernel(const float* __restrict__ inp, const float* __restrict__ conv,
                 ushort* __restrict__ wb, ushort* __restrict__ xb)
{
    const int bid = blockIdx.x, tid = threadIdx.x;
    if (bid >= 1024) {                      // weight transpose tail
        int t = bid - 1024;
        #pragma unroll
        for (int i = 0; i < 16; ++i) {
            int id = i * 256 + tid;
            int oc = id >> 6, c = id & 63;
            wb[t * 4096 + id] = f2bf(conv[(oc * 64 + c) * 9 + t]);
        }
        return;
    }
    const int bb = bid >> 7, y = bid & 127;
    const int cg = tid & 7;                 // chunk (8 channels)
    const int xg = tid >> 3;                // 32 groups of 4 px
    const float* src = inp + ((size_t)(bb * CIN + cg * 8) * HW + y) * HW + xg * 4;
    float4 v[8];                            // 8 independent loads in flight
    #pragma unroll
    for (int k = 0; k < 8; ++k)
        v[k] = *(const float4*)(src + (size_t)k * HW * HW);
    const float* fv = (const float*)v;      // fv[k*4+j] = channel cg*8+k, px xg*4+j
    ushort* dst = xb + (size_t)(bb * HW + y) * HW * 64;
    #pragma unroll
    for (int j = 0; j < 4; ++j) {
        int px = xg * 4 + j;
        uint32_t d0 = (uint32_t)f2bf(fv[0 * 4 + j]) | ((uint32_t)f2bf(fv[1 * 4 + j]) << 16);
        uint32_t d1 = (uint32_t)f2bf(fv[2 * 4 + j]) | ((uint32_t)f2bf(fv[3 * 4 + j]) << 16);
        uint32_t d2 = (uint32_t)f2bf(fv[4 * 4 + j]) | ((uint32_t)f2bf(fv[5 * 4 + j]) << 16);
        uint32_t d3 = (uint32_t)f2bf(fv[6 * 4 + j]) | ((uint32_t)f2bf(fv[7 * 4 + j]) << 16);
        int slot = cg ^ (px & 7);
        *(uint4*)(dst + px * 64 + slot * 8) = make_uint4(d0, d1, d2, d3);
    }
}

// ---------------- main: LDS-staged (async DMA), single-barrier ----------------
// block = (b, y-pair): 256 thr = 4 waves, wave w: yloc=w>>1, xhalf=w&1.
// Wave tile 64 oc x 64 px, 2x2 of mfma_32x32x16_bf16.
// LDS: 4 rows (y0-1..y0+2, clamped; clamp-garbage is masked) x 16 KB = 64 KB.
#define LDS_BYTES 65536

__global__ __launch_bounds__(256, 2)
void iconv_main(const ushort* __restrict__ xb, const ushort* __restrict__ wb,
                const float* __restrict__ mask, const float* __restrict__ bias,
                float* __restrict__ out)
{
    extern __shared__ char smem[];
    ushort* Ls = (ushort*)smem;             // [row 0..3][px 0..127][swizzled 128 B]

    const int tid  = threadIdx.x;
    const int bb   = blockIdx.x >> 6;
    const int y0   = (blockIdx.x & 63) << 1;
    const int lane = tid & 63, l31 = lane & 31, lh = lane >> 5;
    const int w    = tid >> 6;
    const int yloc = w >> 1, xh = w & 1;
    const int y    = y0 + yloc, xw = xh * 64;
    const int x0   = xw + l31, x1 = x0 + 32;

    // ---- async stage: wave w copies row rr=w (16 chunks of 1 KB) ----
    {
        int gy = y0 - 1 + w;
        gy = gy < 0 ? 0 : (gy > HW - 1 ? HW - 1 : gy);
        const ushort* grow = xb + ((size_t)(bb * HW + gy) * HW) * 64;
        ushort* lrow = Ls + w * 8192;
        #pragma unroll
        for (int i = 0; i < 16; ++i) {
            __builtin_amdgcn_global_load_lds(
                (const __attribute__((address_space(1))) uint32_t*)(grow + i * 512 + lane * 8),
                (__attribute__((address_space(3))) uint32_t*)(lrow + i * 512),
                16, 0, 0);
        }
    }

    // ---- eq masks from global mask rows (512 B each, L1/L2-hot) ----
    const float* mrow = mask + ((size_t)bb * HW + y) * HW;
    const float m00 = mrow[x0], m01 = mrow[x1];
    uint32_t bits0 = 0, bits1 = 0;
    #pragma unroll
    for (int t = 0; t < 9; ++t) {
        int dy = t / 3 - 1, dx = t % 3 - 1;
        int ny = y + dy;
        bool vy = (ny >= 0) && (ny < HW);
        int nyc = vy ? ny : y;
        const float* r = mask + ((size_t)bb * HW + nyc) * HW;
        int nx0 = x0 + dx, nx1 = x1 + dx;
        bool ok0 = vy && (nx0 >= 0) && (nx0 < HW);
        bool ok1 = vy && (nx1 >= 0) && (nx1 < HW);
        int c0 = nx0 < 0 ? 0 : (nx0 > HW - 1 ? HW - 1 : nx0);
        int c1 = nx1 < 0 ? 0 : (nx1 > HW - 1 ? HW - 1 : nx1);
        if (ok0 && r[c0] == m00) bits0 |= 1u << t;
        if (ok1 && r[c1] == m01) bits1 |= 1u << t;
    }
    const float norm0 = 9.0f / (float)__popc(bits0);
    const float norm1 = 9.0f / (float)__popc(bits1);

    // ---- fused mask_out (== mask) ----
    float* mout = out + (size_t)NB * OCN * HW * HW + ((size_t)bb * HW + y) * HW;
    mout[x0] = m00;
    mout[x1] = m01;

    // ---- A tap 0 prefetch (global, L1-hot 4 KB/tap) ----
    uint4 Ar[2][8];
    #pragma unroll
    for (int i = 0; i < 8; ++i) {
        int h = i >> 2, ks = i & 3;
        Ar[0][i] = *(const uint4*)(wb + (l31 + h * 32) * 64 + ks * 16 + lh * 8);
    }

    __syncthreads();    // single barrier: drains DMA, publishes LDS rows

    floatx16 acc00 = {0,0,0,0,0,0,0,0,0,0,0,0,0,0,0,0};
    floatx16 acc01 = {0,0,0,0,0,0,0,0,0,0,0,0,0,0,0,0};
    floatx16 acc10 = {0,0,0,0,0,0,0,0,0,0,0,0,0,0,0,0};
    floatx16 acc11 = {0,0,0,0,0,0,0,0,0,0,0,0,0,0,0,0};

    #pragma unroll
    for (int t = 0; t < 9; ++t) {
        const int buf = t & 1;
        if (t < 8) {                        // A prefetch next tap
            const ushort* wp = wb + (t + 1) * 4096;
            #pragma unroll
            for (int i = 0; i < 8; ++i) {
                int h = i >> 2, ks = i & 3;
                Ar[buf ^ 1][i] = *(const uint4*)(wp + (l31 + h * 32) * 64 + ks * 16 + lh * 8);
            }
        }

        const int dy = t / 3 - 1, dx = t % 3 - 1;
        const int rrB = 1 + yloc + dy;      // 0..3
        int p0 = x0 + dx; p0 = p0 < 0 ? 0 : (p0 > HW - 1 ? HW - 1 : p0);
        int p1 = x1 + dx; p1 = p1 < 0 ? 0 : (p1 > HW - 1 ? HW - 1 : p1);
        const ushort* b0b = Ls + rrB * 8192 + p0 * 64;
        const ushort* b1b = Ls + rrB * 8192 + p1 * 64;
        const int sw0 = p0 & 7, sw1 = p1 & 7;
        const uint32_t s0 = ((bits0 >> t) & 1u) ? 0xFFFFFFFFu : 0u;
        const uint32_t s1 = ((bits1 >> t) & 1u) ? 0xFFFFFFFFu : 0u;

        #pragma unroll
        for (int ks = 0; ks < 4; ++ks) {
            F8 a0, a1, b0, b1;
            a0.q = Ar[buf][ks];
            a1.q = Ar[buf][4 + ks];
            b0.q = *(const uint4*)(b0b + (((2 * ks + lh) ^ sw0) * 8));
            b1.q = *(const uint4*)(b1b + (((2 * ks + lh) ^ sw1) * 8));
            b0.d[0] &= s0; b0.d[1] &= s0; b0.d[2] &= s0; b0.d[3] &= s0;
            b1.d[0] &= s1; b1.d[1] &= s1; b1.d[2] &= s1; b1.d[3] &= s1;
            acc00 = __builtin_amdgcn_mfma_f32_32x32x16_bf16(a0.s, b0.s, acc00, 0, 0, 0);
            acc01 = __builtin_amdgcn_mfma_f32_32x32x16_bf16(a0.s, b1.s, acc01, 0, 0, 0);
            acc10 = __builtin_amdgcn_mfma_f32_32x32x16_bf16(a1.s, b0.s, acc10, 0, 0, 0);
            acc11 = __builtin_amdgcn_mfma_f32_32x32x16_bf16(a1.s, b1.s, acc11, 0, 0, 0);
        }
    }

    // ---- epilogue (C/D: col=lane&31, row=(r&3)+8*(r>>2)+4*lh) ----
    float* outp = out + (size_t)bb * OCN * HW * HW + (size_t)y * HW;
    #pragma unroll
    for (int mt = 0; mt < 2; ++mt) {
        #pragma unroll
        for (int nt = 0; nt < 2; ++nt) {
            floatx16 a = (mt == 0) ? (nt == 0 ? acc00 : acc01)
                                   : (nt == 0 ? acc10 : acc11);
            float nm = (nt == 0) ? norm0 : norm1;
            int x = xw + nt * 32 + l31;
            #pragma unroll
            for (int r = 0; r < 16; ++r) {
                int oc = mt * 32 + (r & 3) + 8 * (r >> 2) + 4 * lh;
                outp[(size_t)oc * (HW * HW) + x] = a[r] * nm + bias[oc];
            }
        }
    }
}

extern "C" void kernel_launch(void* const* d_in, const int* in_sizes, int n_in,
                              void* d_out, int out_size, void* d_ws, size_t ws_size,
                              hipStream_t stream) {
    (void)in_sizes; (void)n_in; (void)out_size; (void)ws_size;
    const float* inp  = (const float*)d_in[0];
    const float* mask = (const float*)d_in[1];
    const float* conv = (const float*)d_in[2];
    const float* bias = (const float*)d_in[3];
    float* out = (float*)d_out;

    ushort* wb = (ushort*)d_ws;               // 9*64*64 bf16 = 73,728 B
    ushort* xb = (ushort*)d_ws + 65536;       // swizzled NHWC bf16, 16.8 MB

    hipFuncSetAttribute((const void*)iconv_main,
                        hipFuncAttributeMaxDynamicSharedMemorySize, LDS_BYTES);

    prep_kernel<<<1033, 256, 0, stream>>>(inp, conv, wb, xb);
    iconv_main<<<NB * (HW / 2), 256, LDS_BYTES, stream>>>(xb, wb, mask, bias, out);
}

// Round 5
// 106.241 us; speedup vs baseline: 1.2140x; 1.1036x over previous
//
#include <hip/hip_runtime.h>
#include <stdint.h>

// (B,C,H,W)=(8,64,128,128), OC=64, K=3, stride=1, pad=1, fill=-1.
#define HW   128
#define CIN  64
#define OCN  64
#define NB   8

typedef __attribute__((ext_vector_type(8)))  short short8;
typedef __attribute__((ext_vector_type(16))) float floatx16;

union F8 { short8 s; uint32_t d[4]; uint4 q; };

// round-to-nearest-even f32 -> bf16 (inputs finite)
static __device__ __forceinline__ ushort f2bf(float f) {
    uint32_t u = __float_as_uint(f);
    return (ushort)((u + 0x7FFFu + ((u >> 16) & 1u)) >> 16);
}

// ---------------- wprep: conv -> wb2 in MFMA A-FRAGMENT ORDER ----------------
// wb2 element idx = (((t*4+ks)*2+h)*64 + lane)*8 + j
//   holds conv[oc = (lane&31)+h*32][c = ks*16+(lane>>5)*8+j][tap t]  as bf16.
// => main's A-frag load is wb2 + const + lane*8 : ONE contiguous 1KB segment
//    per instruction instead of 64 scattered 16B L1 transactions.
__global__ __launch_bounds__(256)
void wprep_kernel(const float* __restrict__ conv, ushort* __restrict__ wb2) {
    int idx = blockIdx.x * 256 + threadIdx.x;     // 0..36863
    int j  = idx & 7;
    int l  = (idx >> 3) & 63;
    int h  = (idx >> 9) & 1;
    int ks = (idx >> 10) & 3;
    int t  = idx >> 12;
    int oc = (l & 31) + h * 32;
    int c  = ks * 16 + (l >> 5) * 8 + j;
    wb2[idx] = f2bf(conv[(oc * 64 + c) * 9 + t]);
}

// ---------------- main: fused stage+compute, single barrier ----------------
// block = (b, y-pair): 256 thr = 4 waves; wave w: yloc=w>>1, xhalf=w&1.
// Wave tile 64 oc x 64 px via 2x2 mfma_32x32x16_bf16.
// LDS: 4 staged rows (y0-1..y0+2 clamped; clamp-garbage masked) x 8192 shorts.
// Pixel line = 8 chunks of 16B (8 channels each); chunk ch stored at slot
// ch^(px&7) -> ds_read_b128 B-gather is 8-phase bank-uniform (conflict-free).
#define LDS_BYTES 65536

__global__ __launch_bounds__(256, 2)
void iconv_main(const float* __restrict__ inp, const ushort* __restrict__ wb2,
                const float* __restrict__ mask, const float* __restrict__ bias,
                float* __restrict__ out)
{
    extern __shared__ char smem[];
    ushort* Ls = (ushort*)smem;

    const int tid  = threadIdx.x;
    const int bb   = blockIdx.x >> 6;
    const int y0   = (blockIdx.x & 63) << 1;
    const int lane = tid & 63, l31 = lane & 31, lh = lane >> 5;
    const int w    = tid >> 6;
    const int yloc = w >> 1, xh = w & 1;
    const int y    = y0 + yloc, xw = xh * 64;
    const int x0   = xw + l31, x1 = x0 + 32;

    // ---- staging: NCHW fp32 -> swizzled bf16 LDS, 8-segment load pattern ----
    // thread (cg=tid&7 -> channel chunk, xg=tid>>3 -> 4 pixels)
    {
        const int cg = tid & 7, xg = tid >> 3;
        #pragma unroll
        for (int rr = 0; rr < 4; ++rr) {
            int gy = y0 - 1 + rr;
            gy = gy < 0 ? 0 : (gy > HW - 1 ? HW - 1 : gy);
            const float* src = inp + ((size_t)(bb * CIN + cg * 8) * HW + gy) * HW + xg * 4;
            float4 v[8];                       // 8 independent 16B loads in flight
            #pragma unroll
            for (int k = 0; k < 8; ++k)
                v[k] = *(const float4*)(src + (size_t)k * HW * HW);
            const float* fv = (const float*)v; // fv[k*4+j]: channel cg*8+k, px xg*4+j
            ushort* lrow = Ls + rr * 8192;
            #pragma unroll
            for (int j = 0; j < 4; ++j) {
                int px = xg * 4 + j;
                uint32_t d0 = (uint32_t)f2bf(fv[0 * 4 + j]) | ((uint32_t)f2bf(fv[1 * 4 + j]) << 16);
                uint32_t d1 = (uint32_t)f2bf(fv[2 * 4 + j]) | ((uint32_t)f2bf(fv[3 * 4 + j]) << 16);
                uint32_t d2 = (uint32_t)f2bf(fv[4 * 4 + j]) | ((uint32_t)f2bf(fv[5 * 4 + j]) << 16);
                uint32_t d3 = (uint32_t)f2bf(fv[6 * 4 + j]) | ((uint32_t)f2bf(fv[7 * 4 + j]) << 16);
                int slot = cg ^ (px & 7);
                *(uint4*)(lrow + px * 64 + slot * 8) = make_uint4(d0, d1, d2, d3);
            }
        }
    }

    // ---- eq masks from global mask rows (512 B each, L1/L2-hot) ----
    const float* mrow = mask + ((size_t)bb * HW + y) * HW;
    const float m00 = mrow[x0], m01 = mrow[x1];
    uint32_t bits0 = 0, bits1 = 0;
    #pragma unroll
    for (int t = 0; t < 9; ++t) {
        int dy = t / 3 - 1, dx = t % 3 - 1;
        int ny = y + dy;
        bool vy = (ny >= 0) && (ny < HW);
        int nyc = vy ? ny : y;
        const float* r = mask + ((size_t)bb * HW + nyc) * HW;
        int nx0 = x0 + dx, nx1 = x1 + dx;
        bool ok0 = vy && (nx0 >= 0) && (nx0 < HW);
        bool ok1 = vy && (nx1 >= 0) && (nx1 < HW);
        int c0 = nx0 < 0 ? 0 : (nx0 > HW - 1 ? HW - 1 : nx0);
        int c1 = nx1 < 0 ? 0 : (nx1 > HW - 1 ? HW - 1 : nx1);
        if (ok0 && r[c0] == m00) bits0 |= 1u << t;
        if (ok1 && r[c1] == m01) bits1 |= 1u << t;
    }
    const float norm0 = 9.0f / (float)__popc(bits0);
    const float norm1 = 9.0f / (float)__popc(bits1);

    // ---- fused mask_out (== mask) ----
    float* mout = out + (size_t)NB * OCN * HW * HW + ((size_t)bb * HW + y) * HW;
    mout[x0] = m00;
    mout[x1] = m01;

    // ---- A tap 0 prefetch: fragment-major, lane-contiguous (1 segment/inst) ----
    uint4 Ar[2][8];
    #pragma unroll
    for (int i = 0; i < 8; ++i) {   // i = ks*2+h -> Ar[h*4+ks]
        int ks = i >> 1, h = i & 1;
        Ar[0][h * 4 + ks] = *(const uint4*)(wb2 + (size_t)i * 512 + lane * 8);
    }

    __syncthreads();    // single barrier: staging visible

    floatx16 acc00 = {0,0,0,0,0,0,0,0,0,0,0,0,0,0,0,0};
    floatx16 acc01 = {0,0,0,0,0,0,0,0,0,0,0,0,0,0,0,0};
    floatx16 acc10 = {0,0,0,0,0,0,0,0,0,0,0,0,0,0,0,0};
    floatx16 acc11 = {0,0,0,0,0,0,0,0,0,0,0,0,0,0,0,0};

    #pragma unroll
    for (int t = 0; t < 9; ++t) {
        const int buf = t & 1;
        if (t < 8) {                        // coalesced A prefetch next tap
            const ushort* wp = wb2 + (size_t)(t + 1) * 4096;
            #pragma unroll
            for (int i = 0; i < 8; ++i) {
                int ks = i >> 1, h = i & 1;
                Ar[buf ^ 1][h * 4 + ks] = *(const uint4*)(wp + (size_t)i * 512 + lane * 8);
            }
        }

        const int dy = t / 3 - 1, dx = t % 3 - 1;
        const int rrB = 1 + yloc + dy;      // 0..3
        int p0 = x0 + dx; p0 = p0 < 0 ? 0 : (p0 > HW - 1 ? HW - 1 : p0);
        int p1 = x1 + dx; p1 = p1 < 0 ? 0 : (p1 > HW - 1 ? HW - 1 : p1);
        const ushort* b0b = Ls + rrB * 8192 + p0 * 64;
        const ushort* b1b = Ls + rrB * 8192 + p1 * 64;
        const int sw0 = p0 & 7, sw1 = p1 & 7;
        const uint32_t s0 = ((bits0 >> t) & 1u) ? 0xFFFFFFFFu : 0u;
        const uint32_t s1 = ((bits1 >> t) & 1u) ? 0xFFFFFFFFu : 0u;

        #pragma unroll
        for (int ks = 0; ks < 4; ++ks) {
            F8 a0, a1, b0, b1;
            a0.q = Ar[buf][ks];
            a1.q = Ar[buf][4 + ks];
            b0.q = *(const uint4*)(b0b + (((2 * ks + lh) ^ sw0) * 8));
            b1.q = *(const uint4*)(b1b + (((2 * ks + lh) ^ sw1) * 8));
            b0.d[0] &= s0; b0.d[1] &= s0; b0.d[2] &= s0; b0.d[3] &= s0;
            b1.d[0] &= s1; b1.d[1] &= s1; b1.d[2] &= s1; b1.d[3] &= s1;
            acc00 = __builtin_amdgcn_mfma_f32_32x32x16_bf16(a0.s, b0.s, acc00, 0, 0, 0);
            acc01 = __builtin_amdgcn_mfma_f32_32x32x16_bf16(a0.s, b1.s, acc01, 0, 0, 0);
            acc10 = __builtin_amdgcn_mfma_f32_32x32x16_bf16(a1.s, b0.s, acc10, 0, 0, 0);
            acc11 = __builtin_amdgcn_mfma_f32_32x32x16_bf16(a1.s, b1.s, acc11, 0, 0, 0);
        }
    }

    // ---- epilogue (C/D: col=lane&31, row=(r&3)+8*(r>>2)+4*lh) ----
    float* outp = out + (size_t)bb * OCN * HW * HW + (size_t)y * HW;
    #pragma unroll
    for (int mt = 0; mt < 2; ++mt) {
        #pragma unroll
        for (int nt = 0; nt < 2; ++nt) {
            floatx16 a = (mt == 0) ? (nt == 0 ? acc00 : acc01)
                                   : (nt == 0 ? acc10 : acc11);
            float nm = (nt == 0) ? norm0 : norm1;
            int x = xw + nt * 32 + l31;
            #pragma unroll
            for (int r = 0; r < 16; ++r) {
                int oc = mt * 32 + (r & 3) + 8 * (r >> 2) + 4 * lh;
                outp[(size_t)oc * (HW * HW) + x] = a[r] * nm + bias[oc];
            }
        }
    }
}

extern "C" void kernel_launch(void* const* d_in, const int* in_sizes, int n_in,
                              void* d_out, int out_size, void* d_ws, size_t ws_size,
                              hipStream_t stream) {
    (void)in_sizes; (void)n_in; (void)out_size; (void)ws_size;
    const float* inp  = (const float*)d_in[0];
    const float* mask = (const float*)d_in[1];
    const float* conv = (const float*)d_in[2];
    const float* bias = (const float*)d_in[3];
    float* out = (float*)d_out;

    ushort* wb2 = (ushort*)d_ws;              // 9*4096 bf16 = 73,728 B, fragment-major

    hipFuncSetAttribute((const void*)iconv_main,
                        hipFuncAttributeMaxDynamicSharedMemorySize, LDS_BYTES);

    wprep_kernel<<<144, 256, 0, stream>>>(conv, wb2);
    iconv_main<<<NB * (HW / 2), 256, LDS_BYTES, stream>>>(inp, wb2, mask, bias, out);
}

// Round 6
// 106.217 us; speedup vs baseline: 1.2143x; 1.0002x over previous
//
#include <hip/hip_runtime.h>
#include <stdint.h>

// (B,C,H,W)=(8,64,128,128), OC=64, K=3, stride=1, pad=1, fill=-1.
#define HW   128
#define CIN  64
#define OCN  64
#define NB   8

typedef __attribute__((ext_vector_type(8)))  short short8;
typedef __attribute__((ext_vector_type(16))) float floatx16;

union F8 { short8 s; uint32_t d[4]; uint4 q; };

// round-to-nearest-even f32 -> bf16 (inputs finite)
static __device__ __forceinline__ ushort f2bf(float f) {
    uint32_t u = __float_as_uint(f);
    return (ushort)((u + 0x7FFFu + ((u >> 16) & 1u)) >> 16);
}

// ---------------- wprep: conv -> wb2 in MFMA A-FRAGMENT ORDER ----------------
// wb2 idx = (((t*4+ks)*2+h)*64 + l)*8 + j  holds
// conv[oc=(l&31)+h*32][c=ks*16+(l>>5)*8+j][tap t] as bf16.
// A-frag load in main = wb2 + const + lane*8 : one contiguous 1KB segment/inst.
__global__ __launch_bounds__(256)
void wprep_kernel(const float* __restrict__ conv, ushort* __restrict__ wb2) {
    int idx = blockIdx.x * 256 + threadIdx.x;     // 0..36863
    int j  = idx & 7;
    int l  = (idx >> 3) & 63;
    int h  = (idx >> 9) & 1;
    int ks = (idx >> 10) & 3;
    int t  = idx >> 12;
    int oc = (l & 31) + h * 32;
    int c  = ks * 16 + (l >> 5) * 8 + j;
    wb2[idx] = f2bf(conv[(oc * 64 + c) * 9 + t]);
}

// ---------------- main: fused stage+compute, 512 thr = 8 waves ----------------
// block = (b = bid&7  -> XCD-affine, y-pair = bid>>3): 8 waves.
// wave w: h=w>>2 (oc half), yloc=(w>>1)&1, xh=w&1 ; tile 32 oc x 64 px
// via 2 x mfma_32x32x16_bf16 per K-step (one A frag, two B frags).
// LDS: 4 rows (y0-1..y0+2, clamped; garbage masked) x 8192 shorts = 64 KB.
// Pixel line = 8 chunks of 16 B; chunk ch at slot ch^(px&7)  (bank-uniform b128).
#define LDS_BYTES 65536

__global__ __launch_bounds__(512, 4)
void iconv_main(const float* __restrict__ inp, const ushort* __restrict__ wb2,
                const float* __restrict__ mask, const float* __restrict__ bias,
                float* __restrict__ out)
{
    extern __shared__ char smem[];
    ushort* Ls = (ushort*)smem;

    const int tid  = threadIdx.x;
    const int bb   = blockIdx.x & 7;              // batch -> XCD-local L2 reuse
    const int y0   = (blockIdx.x >> 3) << 1;
    const int lane = tid & 63, l31 = lane & 31, lh = lane >> 5;
    const int w    = tid >> 6;                    // 0..7
    const int h    = w >> 2;                      // oc half
    const int yloc = (w >> 1) & 1, xh = w & 1;
    const int y    = y0 + yloc, xw = xh * 64;
    const int x0   = xw + l31, x1 = x0 + 32;

    // ---- staging: half the threads do rows {0,1}, half rows {2,3} ----
    {
        const int cg = tid & 7, xg = (tid >> 3) & 31, rh = tid >> 8;
        #pragma unroll
        for (int r = 0; r < 2; ++r) {
            int rr = rh * 2 + r;
            int gy = y0 - 1 + rr;
            gy = gy < 0 ? 0 : (gy > HW - 1 ? HW - 1 : gy);
            const float* src = inp + ((size_t)(bb * CIN + cg * 8) * HW + gy) * HW + xg * 4;
            float4 v[8];                       // 8 independent 16B loads in flight
            #pragma unroll
            for (int k = 0; k < 8; ++k)
                v[k] = *(const float4*)(src + (size_t)k * HW * HW);
            const float* fv = (const float*)v; // fv[k*4+j]: ch cg*8+k, px xg*4+j
            ushort* lrow = Ls + rr * 8192;
            #pragma unroll
            for (int j = 0; j < 4; ++j) {
                int px = xg * 4 + j;
                uint32_t d0 = (uint32_t)f2bf(fv[0 * 4 + j]) | ((uint32_t)f2bf(fv[1 * 4 + j]) << 16);
                uint32_t d1 = (uint32_t)f2bf(fv[2 * 4 + j]) | ((uint32_t)f2bf(fv[3 * 4 + j]) << 16);
                uint32_t d2 = (uint32_t)f2bf(fv[4 * 4 + j]) | ((uint32_t)f2bf(fv[5 * 4 + j]) << 16);
                uint32_t d3 = (uint32_t)f2bf(fv[6 * 4 + j]) | ((uint32_t)f2bf(fv[7 * 4 + j]) << 16);
                int slot = cg ^ (px & 7);
                *(uint4*)(lrow + px * 64 + slot * 8) = make_uint4(d0, d1, d2, d3);
            }
        }
    }

    // ---- eq masks from global mask rows (512 B each, L1/L2-hot) ----
    const float* mrow = mask + ((size_t)bb * HW + y) * HW;
    const float m00 = mrow[x0], m01 = mrow[x1];
    uint32_t bits0 = 0, bits1 = 0;
    #pragma unroll
    for (int t = 0; t < 9; ++t) {
        int dy = t / 3 - 1, dx = t % 3 - 1;
        int ny = y + dy;
        bool vy = (ny >= 0) && (ny < HW);
        int nyc = vy ? ny : y;
        const float* r = mask + ((size_t)bb * HW + nyc) * HW;
        int nx0 = x0 + dx, nx1 = x1 + dx;
        bool ok0 = vy && (nx0 >= 0) && (nx0 < HW);
        bool ok1 = vy && (nx1 >= 0) && (nx1 < HW);
        int c0 = nx0 < 0 ? 0 : (nx0 > HW - 1 ? HW - 1 : nx0);
        int c1 = nx1 < 0 ? 0 : (nx1 > HW - 1 ? HW - 1 : nx1);
        if (ok0 && r[c0] == m00) bits0 |= 1u << t;
        if (ok1 && r[c1] == m01) bits1 |= 1u << t;
    }
    const float norm0 = 9.0f / (float)__popc(bits0);
    const float norm1 = 9.0f / (float)__popc(bits1);

    // ---- fused mask_out (== mask); only h==0 waves (avoid dup stores) ----
    if (h == 0) {
        float* mout = out + (size_t)NB * OCN * HW * HW + ((size_t)bb * HW + y) * HW;
        mout[x0] = m00;
        mout[x1] = m01;
    }

    // ---- A tap 0 prefetch: fragment-major, lane-contiguous ----
    uint4 Ar[2][4];
    #pragma unroll
    for (int ks = 0; ks < 4; ++ks)
        Ar[0][ks] = *(const uint4*)(wb2 + (size_t)((ks * 2 + h) * 512) + lane * 8);

    __syncthreads();    // single barrier: staging visible

    floatx16 acc0 = {0,0,0,0,0,0,0,0,0,0,0,0,0,0,0,0};
    floatx16 acc1 = {0,0,0,0,0,0,0,0,0,0,0,0,0,0,0,0};

    #pragma unroll
    for (int t = 0; t < 9; ++t) {
        const int buf = t & 1;
        if (t < 8) {                        // coalesced A prefetch next tap
            const ushort* wp = wb2 + (size_t)(t + 1) * 4096;
            #pragma unroll
            for (int ks = 0; ks < 4; ++ks)
                Ar[buf ^ 1][ks] = *(const uint4*)(wp + (ks * 2 + h) * 512 + lane * 8);
        }

        const int dy = t / 3 - 1, dx = t % 3 - 1;
        const int rrB = 1 + yloc + dy;      // 0..3
        int p0 = x0 + dx; p0 = p0 < 0 ? 0 : (p0 > HW - 1 ? HW - 1 : p0);
        int p1 = x1 + dx; p1 = p1 < 0 ? 0 : (p1 > HW - 1 ? HW - 1 : p1);
        const ushort* b0b = Ls + rrB * 8192 + p0 * 64;
        const ushort* b1b = Ls + rrB * 8192 + p1 * 64;
        const int sw0 = p0 & 7, sw1 = p1 & 7;
        const uint32_t s0 = ((bits0 >> t) & 1u) ? 0xFFFFFFFFu : 0u;
        const uint32_t s1 = ((bits1 >> t) & 1u) ? 0xFFFFFFFFu : 0u;

        #pragma unroll
        for (int ks = 0; ks < 4; ++ks) {
            F8 a, b0, b1;
            a.q  = Ar[buf][ks];
            b0.q = *(const uint4*)(b0b + (((2 * ks + lh) ^ sw0) * 8));
            b1.q = *(const uint4*)(b1b + (((2 * ks + lh) ^ sw1) * 8));
            b0.d[0] &= s0; b0.d[1] &= s0; b0.d[2] &= s0; b0.d[3] &= s0;
            b1.d[0] &= s1; b1.d[1] &= s1; b1.d[2] &= s1; b1.d[3] &= s1;
            acc0 = __builtin_amdgcn_mfma_f32_32x32x16_bf16(a.s, b0.s, acc0, 0, 0, 0);
            acc1 = __builtin_amdgcn_mfma_f32_32x32x16_bf16(a.s, b1.s, acc1, 0, 0, 0);
        }
    }

    // ---- epilogue (C/D: col=lane&31, row=(r&3)+8*(r>>2)+4*lh) ----
    float* outp = out + (size_t)bb * OCN * HW * HW + (size_t)y * HW;
    #pragma unroll
    for (int nt = 0; nt < 2; ++nt) {
        floatx16 a = nt == 0 ? acc0 : acc1;
        float nm   = nt == 0 ? norm0 : norm1;
        int x = xw + nt * 32 + l31;
        #pragma unroll
        for (int r = 0; r < 16; ++r) {
            int oc = h * 32 + (r & 3) + 8 * (r >> 2) + 4 * lh;
            outp[(size_t)oc * (HW * HW) + x] = a[r] * nm + bias[oc];
        }
    }
}

extern "C" void kernel_launch(void* const* d_in, const int* in_sizes, int n_in,
                              void* d_out, int out_size, void* d_ws, size_t ws_size,
                              hipStream_t stream) {
    (void)in_sizes; (void)n_in; (void)out_size; (void)ws_size;
    const float* inp  = (const float*)d_in[0];
    const float* mask = (const float*)d_in[1];
    const float* conv = (const float*)d_in[2];
    const float* bias = (const float*)d_in[3];
    float* out = (float*)d_out;

    ushort* wb2 = (ushort*)d_ws;              // 9*4096 bf16, fragment-major

    hipFuncSetAttribute((const void*)iconv_main,
                        hipFuncAttributeMaxDynamicSharedMemorySize, LDS_BYTES);

    wprep_kernel<<<144, 256, 0, stream>>>(conv, wb2);
    iconv_main<<<NB * (HW / 2), 512, LDS_BYTES, stream>>>(inp, wb2, mask, bias, out);
}